// Round 14
// baseline (352.989 us; speedup 1.0000x reference)
//
#include <hip/hip_runtime.h>
#include <stdint.h>

typedef __bf16  bf16x8 __attribute__((ext_vector_type(8)));
typedef float   f32x4  __attribute__((ext_vector_type(4)));
typedef float   f32x2  __attribute__((ext_vector_type(2)));
typedef unsigned short u16x8 __attribute__((ext_vector_type(8)));

__device__ __forceinline__ unsigned short f2bf(float f) {
  unsigned int u = __float_as_uint(f);
  u += 0x7fffu + ((u >> 16) & 1u);
  return (unsigned short)(u >> 16);
}
__device__ __forceinline__ float bflo(unsigned int v) { return __uint_as_float(v << 16); }
__device__ __forceinline__ float bfhi(unsigned int v) { return __uint_as_float(v & 0xffff0000u); }

// fp8 e4m3 pack/unpack via gfx950 hw converts (encode+decode use the SAME ops,
// so byte/pair ordering is self-consistent; r13-validated end-to-end)
__device__ __forceinline__ f32x2 fp8_dec_lo(unsigned int u) { return __builtin_amdgcn_cvt_pk_f32_fp8(u, false); }
__device__ __forceinline__ f32x2 fp8_dec_hi(unsigned int u) { return __builtin_amdgcn_cvt_pk_f32_fp8(u, true); }
__device__ __forceinline__ unsigned int fp8_enc_lo(float a, float b, unsigned int old) {
  return __builtin_amdgcn_cvt_pk_fp8_f32(a, b, old, false);
}
__device__ __forceinline__ unsigned int fp8_enc_hi(float a, float b, unsigned int old) {
  return __builtin_amdgcn_cvt_pk_fp8_f32(a, b, old, true);
}

// int64-vs-int32 edge detect (4 odd slots all zero <=> int64; P(false)≈1.6e-19).
__device__ __forceinline__ int edges_are_i64(const int* __restrict__ eg) {
  return (eg[1] | eg[3] | eg[5] | eg[7]) == 0;
}

// ---------- fused: x->bf16 + x->fp8 | weight prep | degree histogram ----------
__global__ void phase1_kernel(const float* __restrict__ x, unsigned short* __restrict__ A0,
                              unsigned char* __restrict__ Xq, int n,
                              const int* __restrict__ eg, int* __restrict__ deg, int E,
                              const float* __restrict__ W00, const float* __restrict__ W10,
                              const float* __restrict__ W01, const float* __restrict__ W11,
                              const float* __restrict__ b00, const float* __restrict__ b10,
                              const float* __restrict__ b01, const float* __restrict__ b11,
                              unsigned short* __restrict__ Bt1, unsigned short* __restrict__ Bt2,
                              float* __restrict__ bias1, float* __restrict__ bias2) {
  const int i = blockIdx.x * 256 + threadIdx.x;
  if (i < n * 64) {
    const int row = i >> 6, c4 = i & 63;
    const float4 v = ((const float4*)x)[i];
    ushort4 o;
    o.x = f2bf(v.x); o.y = f2bf(v.y); o.z = f2bf(v.z); o.w = f2bf(v.w);
    *(ushort4*)&A0[(size_t)row * 512 + c4 * 4] = o;
    unsigned int q = 0;
    q = fp8_enc_lo(v.x, v.y, q);
    q = fp8_enc_hi(v.z, v.w, q);
    *(unsigned int*)&Xq[(size_t)row * 256 + c4 * 4] = q;
  }
  if (i < 512 * 512) {
    const int nn = i >> 9, k = i & 511;
    const float v1 = (k < 256) ? W00[k * 512 + nn] : W10[(k - 256) * 512 + nn];
    Bt1[i] = f2bf(v1);
    const float v2 = (nn < 256) ? W01[k * 256 + nn] : W11[k * 256 + (nn - 256)];
    Bt2[i] = f2bf(v2);
    if (i < 512) {
      bias1[i] = b00[i] + b10[i];
      bias2[i] = (i < 256) ? (b01[i] + b11[i]) : 0.f;
    }
  }
  if (i < E) {
    int a, b;
    if (edges_are_i64(eg)) { a = eg[4 * i]; b = eg[4 * i + 2]; }
    else                   { a = eg[2 * i]; b = eg[2 * i + 1]; }
    if ((unsigned)a < (unsigned)n && (unsigned)b < (unsigned)n) {
      atomicAdd(&deg[a], 1);
      atomicAdd(&deg[b], 1);
    }
  }
}

// ---------- scan pass 1: per-block (1024) sums ----------
__global__ void block_sum_kernel(const int* __restrict__ deg, int* __restrict__ bsum, int n) {
  const int t = threadIdx.x;
  const int i = blockIdx.x * 1024 + t;
  int v = (i < n) ? deg[i] : 0;
  #pragma unroll
  for (int d = 32; d > 0; d >>= 1) v += __shfl_xor(v, d);
  __shared__ int ws[16];
  if ((t & 63) == 0) ws[t >> 6] = v;
  __syncthreads();
  if (t < 16) {
    int s = ws[t];
    #pragma unroll
    for (int d = 1; d < 16; d <<= 1) s += __shfl_xor(s, d);
    if (t == 0) bsum[blockIdx.x] = s;
  }
}

// ---------- scan pass 2: exclusive scan of block sums (<=64 blocks) ----------
__global__ void scan_bsum_kernel(int* __restrict__ bsum, int* __restrict__ off, int nb, int n) {
  const int l = threadIdx.x;
  int v = (l < nb) ? bsum[l] : 0;
  const int orig = v;
  #pragma unroll
  for (int d = 1; d < 64; d <<= 1) {
    int u = __shfl_up(v, d);
    if (l >= d) v += u;
  }
  if (l < nb) bsum[l] = v - orig;
  if (l == nb - 1) off[n] = v;
}

// ---------- scan pass 3: final offsets + invdeg + zero curp ----------
__global__ void scan_final_kernel(const int* __restrict__ deg, const int* __restrict__ bsum,
                                  int* __restrict__ off, float* __restrict__ invd,
                                  int* __restrict__ curp, int n) {
  const int t = threadIdx.x;
  const int i = blockIdx.x * 1024 + t;
  const int lane = t & 63, wid = t >> 6;
  const int v = (i < n) ? deg[i] : 0;
  int s = v;
  #pragma unroll
  for (int d = 1; d < 64; d <<= 1) {
    int u = __shfl_up(s, d);
    if (lane >= d) s += u;
  }
  __shared__ int ws[16];
  if (lane == 63) ws[wid] = s;
  __syncthreads();
  if (t < 16) {
    int w = ws[t];
    #pragma unroll
    for (int d = 1; d < 16; d <<= 1) {
      int u = __shfl_up(w, d);
      if (t >= d) w += u;
    }
    ws[t] = w;
  }
  __syncthreads();
  const int add = (wid > 0) ? ws[wid - 1] : 0;
  const int incl = s + add;
  if (i < n) {
    off[i] = bsum[blockIdx.x] + incl - v;
    invd[i] = 1.f / (float)(v > 1 ? v : 1);
    curp[i] = 0;
  }
}

// ---------- CSR fill ----------
__global__ void fill_kernel(const int* __restrict__ eg,
                            const int* __restrict__ off, int* __restrict__ cur,
                            int* __restrict__ adj, int E, int n) {
  const int e = blockIdx.x * 256 + threadIdx.x;
  if (e >= E) return;
  int a, b;
  if (edges_are_i64(eg)) { a = eg[4 * e]; b = eg[4 * e + 2]; }
  else                   { a = eg[2 * e]; b = eg[2 * e + 1]; }
  if ((unsigned)a >= (unsigned)n || (unsigned)b >= (unsigned)n) return;
  int p = atomicAdd(&cur[b], 1); adj[off[b] + p] = a;
  int q = atomicAdd(&cur[a], 1); adj[off[a] + q] = b;
}

// ---------- fp8 gather (r13, proven): tables [n][256] fp8 e4m3 ----------
template<int MODE>
__global__ __launch_bounds__(256) void agg_fp8_kernel(
    const unsigned char* __restrict__ Tq, unsigned short* A0w, float* out,
    const int* __restrict__ adj, const int* __restrict__ off,
    const float* __restrict__ invd, int n) {
  const int node = blockIdx.x * 4 + (threadIdx.x >> 6);
  if (node >= n) return;
  const int lane = threadIdx.x & 63;
  const int rq = lane >> 4;
  const int cq = lane & 15;
  const int s = off[node], e = off[node + 1];
  float acc[16];
  #pragma unroll
  for (int i = 0; i < 16; ++i) acc[i] = 0.f;

  for (int base = s; base < e; base += 64) {
    const int cnt = min(64, e - base);
    const int idxv = (lane < cnt) ? adj[base + lane] : 0;
    for (int j = 0; j < cnt; j += 8) {
      const int s0 = j + rq, s1 = j + 4 + rq;
      const int r0 = __shfl(idxv, s0), r1 = __shfl(idxv, s1);
      uint4 v0 = make_uint4(0u, 0u, 0u, 0u), v1 = v0;
      if (s0 < cnt) v0 = *(const uint4*)&Tq[(size_t)r0 * 256 + cq * 16];
      if (s1 < cnt) v1 = *(const uint4*)&Tq[(size_t)r1 * 256 + cq * 16];
      #pragma unroll
      for (int h = 0; h < 2; ++h) {
        const uint4 v = h ? v1 : v0;
        f32x2 a, b;
        a = fp8_dec_lo(v.x); b = fp8_dec_hi(v.x);
        acc[0] += a[0];  acc[1] += a[1];  acc[2] += b[0];  acc[3] += b[1];
        a = fp8_dec_lo(v.y); b = fp8_dec_hi(v.y);
        acc[4] += a[0];  acc[5] += a[1];  acc[6] += b[0];  acc[7] += b[1];
        a = fp8_dec_lo(v.z); b = fp8_dec_hi(v.z);
        acc[8] += a[0];  acc[9] += a[1];  acc[10] += b[0]; acc[11] += b[1];
        a = fp8_dec_lo(v.w); b = fp8_dec_hi(v.w);
        acc[12] += a[0]; acc[13] += a[1]; acc[14] += b[0]; acc[15] += b[1];
      }
    }
  }
  #pragma unroll
  for (int i = 0; i < 16; ++i) {
    acc[i] += __shfl_xor(acc[i], 16);
    acc[i] += __shfl_xor(acc[i], 32);
  }
  if (rq == 0) {
    const float sc = invd[node];
    if (MODE == 0) {
      u16x8 o0, o1;
      #pragma unroll
      for (int k = 0; k < 8; ++k) { o0[k] = f2bf(acc[k] * sc); o1[k] = f2bf(acc[8 + k] * sc); }
      *(u16x8*)&A0w[(size_t)node * 512 + 256 + cq * 16] = o0;
      *(u16x8*)&A0w[(size_t)node * 512 + 256 + cq * 16 + 8] = o1;
    } else {
      float* po = &out[(size_t)node * 256 + cq * 16];
      #pragma unroll
      for (int k = 0; k < 4; ++k) {
        float4 pv = ((float4*)po)[k];
        pv.x += sc * acc[4 * k + 0]; pv.y += sc * acc[4 * k + 1];
        pv.z += sc * acc[4 * k + 2]; pv.w += sc * acc[4 * k + 3];
        ((float4*)po)[k] = pv;
      }
    }
  }
}

// ---------- barrier-free fused dual-GEMM: 64-row strip, 256 thr / 4 waves ----------
// r13 post-mortem: 1-block/CU lockstep = ~4.2K cyc/K-iter with 320 cyc MFMA ->
// all-pipes-idle barrier stalls. Fix: NO LDS staging for operands. B1/B2 (0.5 MB
// each, L2-resident) and A (no cross-wave reuse) load fragments DIRECTLY
// global->register; compiler pipelines with vmcnt, no barriers inside phases.
// LDS holds only H (cross-wave exchange): [64][512] bf16 = 64 KiB -> 2 blocks/CU.
// Wave w: cols w*128..+128 both phases; acc[4][8] f32x4, all static (rule #20).
// ~3 barriers total. Hl XOR swizzle = r13's proven chunk^=(row&7).
__global__ __launch_bounds__(256, 2) void fused_gemm_kernel(
    const unsigned short* __restrict__ A, const unsigned short* __restrict__ B1,
    const unsigned short* __restrict__ B2,
    const float* __restrict__ bias1, const float* __restrict__ bias2,
    float* __restrict__ Pout, unsigned char* __restrict__ Zq, int M_real) {
  __shared__ unsigned short Hl[64 * 512];   // 64 KiB
  const int t = threadIdx.x;
  const int lane = t & 63;
  const int w = t >> 6;          // wave 0..3
  const int l15 = lane & 15;
  const int lk = lane >> 4;      // k-chunk 0..3
  const int m0 = blockIdx.x * 64;

  // ---------------- phase A: acc1 = A[64][512] @ B1[:, w*128..+128] ----------------
  f32x4 acc1[4][8];
  #pragma unroll
  for (int m = 0; m < 4; ++m)
    #pragma unroll
    for (int nn = 0; nn < 8; ++nn)
      acc1[m][nn] = f32x4{0.f, 0.f, 0.f, 0.f};

  #pragma unroll 1
  for (int kt = 0; kt < 16; ++kt) {
    bf16x8 aF[4], bF[8];
    #pragma unroll
    for (int m = 0; m < 4; ++m)
      aF[m] = *(const bf16x8*)&A[(size_t)(m0 + m * 16 + l15) * 512 + kt * 32 + lk * 8];
    #pragma unroll
    for (int nn = 0; nn < 8; ++nn)
      bF[nn] = *(const bf16x8*)&B1[(size_t)(w * 128 + nn * 16 + l15) * 512 + kt * 32 + lk * 8];
    #pragma unroll
    for (int m = 0; m < 4; ++m)
      #pragma unroll
      for (int nn = 0; nn < 8; ++nn)
        acc1[m][nn] = __builtin_amdgcn_mfma_f32_16x16x32_bf16(aF[m], bF[nn], acc1[m][nn], 0, 0, 0);
  }

  // H (bias+relu, bf16) -> Hl, swizzle chunk ^= (row&7)  [r13-proven pattern]
  #pragma unroll
  for (int nn = 0; nn < 8; ++nn) {
    const int col = w * 128 + nn * 16 + l15;
    const float bc = bias1[col];
    #pragma unroll
    for (int m = 0; m < 4; ++m) {
      #pragma unroll
      for (int r = 0; r < 4; ++r) {
        const int row = m * 16 + lk * 4 + r;   // 0..63
        float y = acc1[m][nn][r] + bc;
        y = y > 0.f ? y : 0.f;
        Hl[row * 512 + (((col >> 3) ^ (row & 7)) << 3) + (col & 7)] = f2bf(y);
      }
    }
  }
  __syncthreads();

  // ---------------- phase B: acc2 = H @ B2[:, w*128..+128] ----------------
  f32x4 acc2[4][8];
  #pragma unroll
  for (int m = 0; m < 4; ++m)
    #pragma unroll
    for (int nn = 0; nn < 8; ++nn)
      acc2[m][nn] = f32x4{0.f, 0.f, 0.f, 0.f};

  #pragma unroll 1
  for (int kt = 0; kt < 16; ++kt) {
    bf16x8 aF2[4], bF2[8];
    #pragma unroll
    for (int m = 0; m < 4; ++m) {
      const int row = m * 16 + l15;
      const int chk = (kt * 4 + lk) ^ (row & 7);
      aF2[m] = *(const bf16x8*)&Hl[row * 512 + chk * 8];
    }
    #pragma unroll
    for (int nn = 0; nn < 8; ++nn)
      bF2[nn] = *(const bf16x8*)&B2[(size_t)(w * 128 + nn * 16 + l15) * 512 + kt * 32 + lk * 8];
    #pragma unroll
    for (int m = 0; m < 4; ++m)
      #pragma unroll
      for (int nn = 0; nn < 8; ++nn)
        acc2[m][nn] = __builtin_amdgcn_mfma_f32_16x16x32_bf16(aF2[m], bF2[nn], acc2[m][nn], 0, 0, 0);
  }
  __syncthreads();   // all Hl reads done -> Hl reusable as repack buffer

  if (w < 2) {
    // P = C + bias2 (out cols 0..255), direct fp32 stores, row-guarded
    #pragma unroll
    for (int nn = 0; nn < 8; ++nn) {
      const int gcol = w * 128 + nn * 16 + l15;
      const float bc = bias2[gcol];
      #pragma unroll
      for (int m = 0; m < 4; ++m) {
        #pragma unroll
        for (int r = 0; r < 4; ++r) {
          const int grow = m0 + m * 16 + lk * 4 + r;
          if (grow < M_real) Pout[(size_t)grow * 256 + gcol] = acc2[m][nn][r] + bc;
        }
      }
    }
  } else {
    // Z (out cols 256..511): wave-local bf16 repack into Hl region (w-2)*16K
    unsigned short* rep = &Hl[(w - 2) * 8192];
    #pragma unroll
    for (int nn = 0; nn < 8; ++nn) {
      const int lcol = nn * 16 + l15;            // 0..127
      #pragma unroll
      for (int m = 0; m < 4; ++m) {
        #pragma unroll
        for (int r = 0; r < 4; ++r) {
          const int lr = m * 16 + lk * 4 + r;    // 0..63
          rep[lr * 128 + (lcol ^ (((lr >> 2) & 7) << 4))] = f2bf(acc2[m][nn][r]);
        }
      }
    }
  }
  __syncthreads();

  // Zq readout: 64 rows x 256 fp8 (16 KB), coalesced uint2 stores
  #pragma unroll
  for (int p = 0; p < 8; ++p) {
    const int idx = p * 256 + t;                 // 0..2047
    const int tr = idx >> 5;                     // 0..63
    const int it = idx & 31;
    const int g = it >> 4;                       // 0/1 -> col half
    const int cb = (it & 15) * 8;                // 0..120
    const uint4 v = *(const uint4*)&Hl[g * 8192 + tr * 128 + (cb ^ (((tr >> 2) & 7) << 4))];
    unsigned int lo = 0, hi = 0;
    lo = fp8_enc_lo(bflo(v.x), bfhi(v.x), lo);
    lo = fp8_enc_hi(bflo(v.y), bfhi(v.y), lo);
    hi = fp8_enc_lo(bflo(v.z), bfhi(v.z), hi);
    hi = fp8_enc_hi(bflo(v.w), bfhi(v.w), hi);
    *(uint2*)&Zq[(size_t)(m0 + tr) * 256 + g * 128 + cb] = make_uint2(lo, hi);
  }
}

extern "C" void kernel_launch(void* const* d_in, const int* in_sizes, int n_in,
                              void* d_out, int out_size, void* d_ws, size_t ws_size,
                              hipStream_t stream) {
  const float* x   = (const float*)d_in[0];
  const int* edges = (const int*)d_in[1];
  const float* W00 = (const float*)d_in[2];
  const float* b00 = (const float*)d_in[3];
  const float* W10 = (const float*)d_in[4];
  const float* b10 = (const float*)d_in[5];
  const float* W01 = (const float*)d_in[6];
  const float* b01 = (const float*)d_in[7];
  const float* W11 = (const float*)d_in[8];
  const float* b11 = (const float*)d_in[9];
  float* out = (float*)d_out;

  const int n = in_sizes[0] / 256;   // 50000 nodes
  const int E = in_sizes[1] / 2;     // 400000 edges
  const int nstrip = (n + 63) / 64;  // 782 strips of 64 rows
  const int Mp = nstrip * 64;

  char* p = (char*)d_ws;
  auto alloc = [&](size_t bytes) { char* r = p; p += (bytes + 255) & ~(size_t)255; return r; };
  unsigned short* A0  = (unsigned short*)alloc((size_t)Mp * 512 * 2);
  unsigned char*  Xq  = (unsigned char*)alloc((size_t)Mp * 256);
  unsigned char*  Zq  = (unsigned char*)alloc((size_t)Mp * 256);
  unsigned short* Bt1 = (unsigned short*)alloc(512 * 512 * 2);
  unsigned short* Bt2 = (unsigned short*)alloc(512 * 512 * 2);
  float* bias1 = (float*)alloc(512 * 4);
  float* bias2 = (float*)alloc(512 * 4);
  int*   deg   = (int*)alloc((size_t)n * 4);
  int*   curp  = (int*)alloc((size_t)n * 4);
  int*   off   = (int*)alloc((size_t)(n + 1) * 4);
  int*   bsum  = (int*)alloc(256 * 4);
  float* invd  = (float*)alloc((size_t)n * 4);
  int*   adj   = (int*)alloc((size_t)2 * E * 4);

  hipMemsetAsync(deg, 0, (size_t)n * 4, stream);

  const int p1_blocks = (n * 64 + 255) / 256;
  phase1_kernel<<<p1_blocks, 256, 0, stream>>>(x, A0, Xq, n, edges, deg, E,
                                               W00, W10, W01, W11, b00, b10, b01, b11,
                                               Bt1, Bt2, bias1, bias2);

  const int nb = (n + 1023) / 1024;
  block_sum_kernel<<<nb, 1024, 0, stream>>>(deg, bsum, n);
  scan_bsum_kernel<<<1, 64, 0, stream>>>(bsum, off, nb, n);
  scan_final_kernel<<<nb, 1024, 0, stream>>>(deg, bsum, off, invd, curp, n);
  fill_kernel<<<(E + 255) / 256, 256, 0, stream>>>(edges, off, curp, adj, E, n);

  agg_fp8_kernel<0><<<(n + 3) / 4, 256, 0, stream>>>(Xq, A0, nullptr, adj, off, invd, n);

  fused_gemm_kernel<<<nstrip, 256, 0, stream>>>(A0, Bt1, Bt2, bias1, bias2, out, Zq, n);

  agg_fp8_kernel<1><<<(n + 3) / 4, 256, 0, stream>>>(Zq, nullptr, out, adj, off, invd, n);
}

// Round 15
// 276.070 us; speedup vs baseline: 1.2786x; 1.2786x over previous
//
#include <hip/hip_runtime.h>
#include <stdint.h>

typedef __bf16  bf16x8 __attribute__((ext_vector_type(8)));
typedef float   f32x4  __attribute__((ext_vector_type(4)));
typedef float   f32x2  __attribute__((ext_vector_type(2)));
typedef unsigned short u16x8 __attribute__((ext_vector_type(8)));

__device__ __forceinline__ unsigned short f2bf(float f) {
  unsigned int u = __float_as_uint(f);
  u += 0x7fffu + ((u >> 16) & 1u);
  return (unsigned short)(u >> 16);
}
__device__ __forceinline__ float bflo(unsigned int v) { return __uint_as_float(v << 16); }
__device__ __forceinline__ float bfhi(unsigned int v) { return __uint_as_float(v & 0xffff0000u); }

// fp8 e4m3 pack/unpack via gfx950 hw converts (encode+decode use the SAME ops,
// so byte/pair ordering is self-consistent; r13-validated end-to-end)
__device__ __forceinline__ f32x2 fp8_dec_lo(unsigned int u) { return __builtin_amdgcn_cvt_pk_f32_fp8(u, false); }
__device__ __forceinline__ f32x2 fp8_dec_hi(unsigned int u) { return __builtin_amdgcn_cvt_pk_f32_fp8(u, true); }
__device__ __forceinline__ unsigned int fp8_enc_lo(float a, float b, unsigned int old) {
  return __builtin_amdgcn_cvt_pk_fp8_f32(a, b, old, false);
}
__device__ __forceinline__ unsigned int fp8_enc_hi(float a, float b, unsigned int old) {
  return __builtin_amdgcn_cvt_pk_fp8_f32(a, b, old, true);
}

__device__ __forceinline__ void glds16(const unsigned short* g, unsigned short* l) {
  __builtin_amdgcn_global_load_lds(
      (const __attribute__((address_space(1))) unsigned int*)g,
      (__attribute__((address_space(3))) unsigned int*)l, 16, 0, 0);
}

// int64-vs-int32 edge detect (4 odd slots all zero <=> int64; P(false)≈1.6e-19).
__device__ __forceinline__ int edges_are_i64(const int* __restrict__ eg) {
  return (eg[1] | eg[3] | eg[5] | eg[7]) == 0;
}

// ---------- fused: x->bf16 + x->fp8 | weight prep | degree histogram ----------
__global__ void phase1_kernel(const float* __restrict__ x, unsigned short* __restrict__ A0,
                              unsigned char* __restrict__ Xq, int n,
                              const int* __restrict__ eg, int* __restrict__ deg, int E,
                              const float* __restrict__ W00, const float* __restrict__ W10,
                              const float* __restrict__ W01, const float* __restrict__ W11,
                              const float* __restrict__ b00, const float* __restrict__ b10,
                              const float* __restrict__ b01, const float* __restrict__ b11,
                              unsigned short* __restrict__ Bt1, unsigned short* __restrict__ Bt2,
                              float* __restrict__ bias1, float* __restrict__ bias2) {
  const int i = blockIdx.x * 256 + threadIdx.x;
  if (i < n * 64) {
    const int row = i >> 6, c4 = i & 63;
    const float4 v = ((const float4*)x)[i];
    ushort4 o;
    o.x = f2bf(v.x); o.y = f2bf(v.y); o.z = f2bf(v.z); o.w = f2bf(v.w);
    *(ushort4*)&A0[(size_t)row * 512 + c4 * 4] = o;
    unsigned int q = 0;
    q = fp8_enc_lo(v.x, v.y, q);
    q = fp8_enc_hi(v.z, v.w, q);
    *(unsigned int*)&Xq[(size_t)row * 256 + c4 * 4] = q;
  }
  if (i < 512 * 512) {
    const int nn = i >> 9, k = i & 511;
    const float v1 = (k < 256) ? W00[k * 512 + nn] : W10[(k - 256) * 512 + nn];
    Bt1[i] = f2bf(v1);
    const float v2 = (nn < 256) ? W01[k * 256 + nn] : W11[k * 256 + (nn - 256)];
    Bt2[i] = f2bf(v2);
    if (i < 512) {
      bias1[i] = b00[i] + b10[i];
      bias2[i] = (i < 256) ? (b01[i] + b11[i]) : 0.f;
    }
  }
  if (i < E) {
    int a, b;
    if (edges_are_i64(eg)) { a = eg[4 * i]; b = eg[4 * i + 2]; }
    else                   { a = eg[2 * i]; b = eg[2 * i + 1]; }
    if ((unsigned)a < (unsigned)n && (unsigned)b < (unsigned)n) {
      atomicAdd(&deg[a], 1);
      atomicAdd(&deg[b], 1);
    }
  }
}

// ---------- scan pass 1: per-block (1024) sums ----------
__global__ void block_sum_kernel(const int* __restrict__ deg, int* __restrict__ bsum, int n) {
  const int t = threadIdx.x;
  const int i = blockIdx.x * 1024 + t;
  int v = (i < n) ? deg[i] : 0;
  #pragma unroll
  for (int d = 32; d > 0; d >>= 1) v += __shfl_xor(v, d);
  __shared__ int ws[16];
  if ((t & 63) == 0) ws[t >> 6] = v;
  __syncthreads();
  if (t < 16) {
    int s = ws[t];
    #pragma unroll
    for (int d = 1; d < 16; d <<= 1) s += __shfl_xor(s, d);
    if (t == 0) bsum[blockIdx.x] = s;
  }
}

// ---------- scan pass 2: exclusive scan of block sums (<=64 blocks) ----------
__global__ void scan_bsum_kernel(int* __restrict__ bsum, int* __restrict__ off, int nb, int n) {
  const int l = threadIdx.x;
  int v = (l < nb) ? bsum[l] : 0;
  const int orig = v;
  #pragma unroll
  for (int d = 1; d < 64; d <<= 1) {
    int u = __shfl_up(v, d);
    if (l >= d) v += u;
  }
  if (l < nb) bsum[l] = v - orig;
  if (l == nb - 1) off[n] = v;
}

// ---------- scan pass 3: final offsets + invdeg + zero curp ----------
__global__ void scan_final_kernel(const int* __restrict__ deg, const int* __restrict__ bsum,
                                  int* __restrict__ off, float* __restrict__ invd,
                                  int* __restrict__ curp, int n) {
  const int t = threadIdx.x;
  const int i = blockIdx.x * 1024 + t;
  const int lane = t & 63, wid = t >> 6;
  const int v = (i < n) ? deg[i] : 0;
  int s = v;
  #pragma unroll
  for (int d = 1; d < 64; d <<= 1) {
    int u = __shfl_up(s, d);
    if (lane >= d) s += u;
  }
  __shared__ int ws[16];
  if (lane == 63) ws[wid] = s;
  __syncthreads();
  if (t < 16) {
    int w = ws[t];
    #pragma unroll
    for (int d = 1; d < 16; d <<= 1) {
      int u = __shfl_up(w, d);
      if (t >= d) w += u;
    }
    ws[t] = w;
  }
  __syncthreads();
  const int add = (wid > 0) ? ws[wid - 1] : 0;
  const int incl = s + add;
  if (i < n) {
    off[i] = bsum[blockIdx.x] + incl - v;
    invd[i] = 1.f / (float)(v > 1 ? v : 1);
    curp[i] = 0;
  }
}

// ---------- CSR fill ----------
__global__ void fill_kernel(const int* __restrict__ eg,
                            const int* __restrict__ off, int* __restrict__ cur,
                            int* __restrict__ adj, int E, int n) {
  const int e = blockIdx.x * 256 + threadIdx.x;
  if (e >= E) return;
  int a, b;
  if (edges_are_i64(eg)) { a = eg[4 * e]; b = eg[4 * e + 2]; }
  else                   { a = eg[2 * e]; b = eg[2 * e + 1]; }
  if ((unsigned)a >= (unsigned)n || (unsigned)b >= (unsigned)n) return;
  int p = atomicAdd(&cur[b], 1); adj[off[b] + p] = a;
  int q = atomicAdd(&cur[a], 1); adj[off[a] + q] = b;
}

// ---------- fp8 gather (r13, proven): tables [n][256] fp8 e4m3 ----------
template<int MODE>
__global__ __launch_bounds__(256) void agg_fp8_kernel(
    const unsigned char* __restrict__ Tq, unsigned short* A0w, float* out,
    const int* __restrict__ adj, const int* __restrict__ off,
    const float* __restrict__ invd, int n) {
  const int node = blockIdx.x * 4 + (threadIdx.x >> 6);
  if (node >= n) return;
  const int lane = threadIdx.x & 63;
  const int rq = lane >> 4;
  const int cq = lane & 15;
  const int s = off[node], e = off[node + 1];
  float acc[16];
  #pragma unroll
  for (int i = 0; i < 16; ++i) acc[i] = 0.f;

  for (int base = s; base < e; base += 64) {
    const int cnt = min(64, e - base);
    const int idxv = (lane < cnt) ? adj[base + lane] : 0;
    for (int j = 0; j < cnt; j += 8) {
      const int s0 = j + rq, s1 = j + 4 + rq;
      const int r0 = __shfl(idxv, s0), r1 = __shfl(idxv, s1);
      uint4 v0 = make_uint4(0u, 0u, 0u, 0u), v1 = v0;
      if (s0 < cnt) v0 = *(const uint4*)&Tq[(size_t)r0 * 256 + cq * 16];
      if (s1 < cnt) v1 = *(const uint4*)&Tq[(size_t)r1 * 256 + cq * 16];
      #pragma unroll
      for (int h = 0; h < 2; ++h) {
        const uint4 v = h ? v1 : v0;
        f32x2 a, b;
        a = fp8_dec_lo(v.x); b = fp8_dec_hi(v.x);
        acc[0] += a[0];  acc[1] += a[1];  acc[2] += b[0];  acc[3] += b[1];
        a = fp8_dec_lo(v.y); b = fp8_dec_hi(v.y);
        acc[4] += a[0];  acc[5] += a[1];  acc[6] += b[0];  acc[7] += b[1];
        a = fp8_dec_lo(v.z); b = fp8_dec_hi(v.z);
        acc[8] += a[0];  acc[9] += a[1];  acc[10] += b[0]; acc[11] += b[1];
        a = fp8_dec_lo(v.w); b = fp8_dec_hi(v.w);
        acc[12] += a[0]; acc[13] += a[1]; acc[14] += b[0]; acc[15] += b[1];
      }
    }
  }
  #pragma unroll
  for (int i = 0; i < 16; ++i) {
    acc[i] += __shfl_xor(acc[i], 16);
    acc[i] += __shfl_xor(acc[i], 32);
  }
  if (rq == 0) {
    const float sc = invd[node];
    if (MODE == 0) {
      u16x8 o0, o1;
      #pragma unroll
      for (int k = 0; k < 8; ++k) { o0[k] = f2bf(acc[k] * sc); o1[k] = f2bf(acc[8 + k] * sc); }
      *(u16x8*)&A0w[(size_t)node * 512 + 256 + cq * 16] = o0;
      *(u16x8*)&A0w[(size_t)node * 512 + 256 + cq * 16 + 8] = o1;
    } else {
      float* po = &out[(size_t)node * 256 + cq * 16];
      #pragma unroll
      for (int k = 0; k < 4; ++k) {
        float4 pv = ((float4*)po)[k];
        pv.x += sc * acc[4 * k + 0]; pv.y += sc * acc[4 * k + 1];
        pv.z += sc * acc[4 * k + 2]; pv.w += sc * acc[4 * k + 3];
        ((float4*)po)[k] = pv;
      }
    }
  }
}

// ---------- fused dual-GEMM (r13, proven best): per 128-row strip ----------
// Phase A: H = relu(A0 @ B1 + bias1) in regs, then H -> LDS bf16 [128][512].
// Phase B: all 4 col-groups per K-step; B2 [512][32] single-buffer panel.
// Z output quantized to fp8 (Zq). Rule #20: all acc loops fully unrolled.
// r14 lesson: LDS staging is load-bearing — global->reg B loads leave ~200cyc
// L2 latency unhidden at 8 waves/CU (130 -> 211us). Keep r13 structure.
__global__ __launch_bounds__(512, 1) void fused_gemm_kernel(
    const unsigned short* __restrict__ A, const unsigned short* __restrict__ B1,
    const unsigned short* __restrict__ B2,
    const float* __restrict__ bias1, const float* __restrict__ bias2,
    float* __restrict__ Pout, unsigned char* __restrict__ Zq, int M_real) {
  __shared__ __attribute__((aligned(16))) char smem[163840];
  unsigned short* sA  = (unsigned short*)smem;              // [2][128*64]
  unsigned short* sB  = (unsigned short*)(smem + 32768);    // [2][256*64]
  unsigned short* Hl  = (unsigned short*)smem;              // [128][512]
  unsigned short* sB2 = (unsigned short*)(smem + 131072);   // [512][32] single buf
  const int t = threadIdx.x;
  const int lane = t & 63;
  const int wid = t >> 6;
  const int wr = wid >> 2;      // 0..1 -> 64-row strip
  const int wc = wid & 3;       // 0..3 -> 64-col (A) / 32-col (B) strip
  const int m0 = blockIdx.x * 128;

  // ---------------- phase A ----------------
  f32x4 acc1[2][4][4];
  #pragma unroll
  for (int c = 0; c < 2; ++c)
    #pragma unroll
    for (int m = 0; m < 4; ++m)
      #pragma unroll
      for (int n = 0; n < 4; ++n)
        acc1[c][m][n] = f32x4{0.f, 0.f, 0.f, 0.f};

  #pragma unroll
  for (int nc1 = 0; nc1 < 2; ++nc1) {
    auto stageA = [&](int buf, int kt) {
      #pragma unroll
      for (int i = 0; i < 2; ++i) {
        const int row = (t >> 3) + i * 64;            // 0..127
        const int c = (t & 7) ^ (row & 7);
        glds16(A + (size_t)(m0 + row) * 512 + kt * 64 + c * 8,
               &sA[buf * 8192 + (i * 512 + t) * 8]);
      }
      #pragma unroll
      for (int i = 0; i < 4; ++i) {
        const int row = (t >> 3) + i * 64;            // 0..255
        const int c = (t & 7) ^ (row & 7);
        glds16(B1 + (size_t)(nc1 * 256 + row) * 512 + kt * 64 + c * 8,
               &sB[buf * 16384 + (i * 512 + t) * 8]);
      }
    };
    stageA(0, 0);
    __syncthreads();
    #pragma unroll 1
    for (int kt = 0; kt < 8; ++kt) {
      if (kt < 7) stageA((kt + 1) & 1, kt + 1);
      const int buf = kt & 1;
      #pragma unroll
      for (int kk = 0; kk < 2; ++kk) {
        bf16x8 aF[4], bF[4];
        #pragma unroll
        for (int m = 0; m < 4; ++m) {
          const int row = wr * 64 + m * 16 + (lane & 15);
          const int sl = (kk * 4 + (lane >> 4)) ^ (row & 7);
          aF[m] = *(const bf16x8*)&sA[buf * 8192 + row * 64 + sl * 8];
        }
        #pragma unroll
        for (int n = 0; n < 4; ++n) {
          const int rl = wc * 64 + n * 16 + (lane & 15);
          const int sl = (kk * 4 + (lane >> 4)) ^ (rl & 7);
          bF[n] = *(const bf16x8*)&sB[buf * 16384 + rl * 64 + sl * 8];
        }
        #pragma unroll
        for (int m = 0; m < 4; ++m)
          #pragma unroll
          for (int n = 0; n < 4; ++n)
            acc1[nc1][m][n] = __builtin_amdgcn_mfma_f32_16x16x32_bf16(aF[m], bF[n], acc1[nc1][m][n], 0, 0, 0);
      }
      __syncthreads();
    }
  }

  // ---------------- H (bias+relu, bf16) -> LDS, chunk^=(row&7) ----------------
  #pragma unroll
  for (int nc1 = 0; nc1 < 2; ++nc1) {
    #pragma unroll
    for (int n = 0; n < 4; ++n) {
      const int col = nc1 * 256 + wc * 64 + n * 16 + (lane & 15);
      const float bc = bias1[col];
      #pragma unroll
      for (int m = 0; m < 4; ++m) {
        #pragma unroll
        for (int r = 0; r < 4; ++r) {
          const int row = wr * 64 + m * 16 + (lane >> 4) * 4 + r;
          float y = acc1[nc1][m][n][r] + bc;
          y = y > 0.f ? y : 0.f;
          Hl[row * 512 + (((col >> 3) ^ (row & 7)) << 3) + (col & 7)] = f2bf(y);
        }
      }
    }
  }
  __syncthreads();

  // ---------------- phase B: all 4 col-groups per K-step ----------------
  f32x4 acc2[4][4][2];
  #pragma unroll
  for (int g = 0; g < 4; ++g)
    #pragma unroll
    for (int m = 0; m < 4; ++m)
      #pragma unroll
      for (int n = 0; n < 2; ++n)
        acc2[g][m][n] = f32x4{0.f, 0.f, 0.f, 0.f};

  #pragma unroll 1
  for (int kt = 0; kt < 16; ++kt) {
    __syncthreads();   // previous step's sB2 reads done before overwrite
    #pragma unroll
    for (int i = 0; i < 4; ++i) {
      const int idx = i * 512 + t;          // 0..2047
      const int row = idx >> 2;             // 0..511
      const int c = (idx & 3) ^ ((row >> 1) & 3);
      glds16(B2 + (size_t)row * 512 + kt * 32 + c * 8, &sB2[idx * 8]);
    }
    __syncthreads();   // drains vmcnt -> sB2 ready
    bf16x8 aF2[4];
    #pragma unroll
    for (int m = 0; m < 4; ++m) {
      const int hr = wr * 64 + m * 16 + (lane & 15);
      const int chk = (kt * 4 + (lane >> 4)) ^ (hr & 7);
      aF2[m] = *(const bf16x8*)&Hl[hr * 512 + chk * 8];
    }
    #pragma unroll
    for (int g = 0; g < 4; ++g) {
      bf16x8 bF2[2];
      #pragma unroll
      for (int n = 0; n < 2; ++n) {
        const int rl = g * 128 + wc * 32 + n * 16 + (lane & 15);
        const int sl = (lane >> 4) ^ ((rl >> 1) & 3);
        bF2[n] = *(const bf16x8*)&sB2[rl * 32 + sl * 8];
      }
      #pragma unroll
      for (int m = 0; m < 4; ++m)
        #pragma unroll
        for (int n = 0; n < 2; ++n)
          acc2[g][m][n] = __builtin_amdgcn_mfma_f32_16x16x32_bf16(aF2[m], bF2[n], acc2[g][m][n], 0, 0, 0);
    }
  }
  __syncthreads();

  // P = C + bias2 (groups 0,1): direct fp32 stores, row-guarded (static g)
  #pragma unroll
  for (int g = 0; g < 2; ++g) {
    #pragma unroll
    for (int n = 0; n < 2; ++n) {
      const int gcol = g * 128 + wc * 32 + n * 16 + (lane & 15);
      const float bc = bias2[gcol];
      #pragma unroll
      for (int m = 0; m < 4; ++m) {
        #pragma unroll
        for (int r = 0; r < 4; ++r) {
          const int grow = m0 + wr * 64 + m * 16 + (lane >> 4) * 4 + r;
          if (grow < M_real) Pout[(size_t)grow * 256 + gcol] = acc2[g][m][n][r] + bc;
        }
      }
    }
  }

  // Z (groups 2,3): bf16 repack in sB2 (proven layout), then fp8-encode at store
  #pragma unroll
  for (int g = 2; g < 4; ++g) {
    unsigned short* rep = sB2;
    #pragma unroll
    for (int n = 0; n < 2; ++n) {
      const int lcol = wc * 32 + n * 16 + (lane & 15);
      #pragma unroll
      for (int m = 0; m < 4; ++m) {
        #pragma unroll
        for (int r = 0; r < 4; ++r) {
          const int lr = wr * 64 + m * 16 + (lane >> 4) * 4 + r;   // 0..127
          rep[lr * 128 + (lcol ^ (((lr >> 2) & 7) << 4))] = f2bf(acc2[g][m][n][r]);
        }
      }
    }
    __syncthreads();
    #pragma unroll
    for (int p = 0; p < 4; ++p) {
      const int idx = p * 512 + t;              // 0..2047
      const int tr = idx >> 4;                  // 0..127
      const int cb = (idx & 15) * 8;            // 0..120
      const uint4 v = *(const uint4*)&rep[tr * 128 + (cb ^ (((tr >> 2) & 7) << 4))];
      unsigned int lo = 0, hi = 0;
      lo = fp8_enc_lo(bflo(v.x), bfhi(v.x), lo);
      lo = fp8_enc_hi(bflo(v.y), bfhi(v.y), lo);
      hi = fp8_enc_lo(bflo(v.z), bfhi(v.z), hi);
      hi = fp8_enc_hi(bflo(v.w), bfhi(v.w), hi);
      *(uint2*)&Zq[(size_t)(m0 + tr) * 256 + (g - 2) * 128 + cb] = make_uint2(lo, hi);
    }
    __syncthreads();
  }
}

extern "C" void kernel_launch(void* const* d_in, const int* in_sizes, int n_in,
                              void* d_out, int out_size, void* d_ws, size_t ws_size,
                              hipStream_t stream) {
  const float* x   = (const float*)d_in[0];
  const int* edges = (const int*)d_in[1];
  const float* W00 = (const float*)d_in[2];
  const float* b00 = (const float*)d_in[3];
  const float* W10 = (const float*)d_in[4];
  const float* b10 = (const float*)d_in[5];
  const float* W01 = (const float*)d_in[6];
  const float* b01 = (const float*)d_in[7];
  const float* W11 = (const float*)d_in[8];
  const float* b11 = (const float*)d_in[9];
  float* out = (float*)d_out;

  const int n = in_sizes[0] / 256;   // 50000 nodes
  const int E = in_sizes[1] / 2;     // 400000 edges
  const int nstrip = (n + 127) / 128;         // 391 strips
  const int Mp = nstrip * 128;

  char* p = (char*)d_ws;
  auto alloc = [&](size_t bytes) { char* r = p; p += (bytes + 255) & ~(size_t)255; return r; };
  unsigned short* A0  = (unsigned short*)alloc((size_t)Mp * 512 * 2);
  unsigned char*  Xq  = (unsigned char*)alloc((size_t)Mp * 256);
  unsigned char*  Zq  = (unsigned char*)alloc((size_t)Mp * 256);
  unsigned short* Bt1 = (unsigned short*)alloc(512 * 512 * 2);
  unsigned short* Bt2 = (unsigned short*)alloc(512 * 512 * 2);
  float* bias1 = (float*)alloc(512 * 4);
  float* bias2 = (float*)alloc(512 * 4);
  int*   deg   = (int*)alloc((size_t)n * 4);
  int*   curp  = (int*)alloc((size_t)n * 4);
  int*   off   = (int*)alloc((size_t)(n + 1) * 4);
  int*   bsum  = (int*)alloc(256 * 4);
  float* invd  = (float*)alloc((size_t)n * 4);
  int*   adj   = (int*)alloc((size_t)2 * E * 4);

  hipMemsetAsync(deg, 0, (size_t)n * 4, stream);

  const int p1_blocks = (n * 64 + 255) / 256;
  phase1_kernel<<<p1_blocks, 256, 0, stream>>>(x, A0, Xq, n, edges, deg, E,
                                               W00, W10, W01, W11, b00, b10, b01, b11,
                                               Bt1, Bt2, bias1, bias2);

  const int nb = (n + 1023) / 1024;
  block_sum_kernel<<<nb, 1024, 0, stream>>>(deg, bsum, n);
  scan_bsum_kernel<<<1, 64, 0, stream>>>(bsum, off, nb, n);
  scan_final_kernel<<<nb, 1024, 0, stream>>>(deg, bsum, off, invd, curp, n);
  fill_kernel<<<(E + 255) / 256, 256, 0, stream>>>(edges, off, curp, adj, E, n);

  agg_fp8_kernel<0><<<(n + 3) / 4, 256, 0, stream>>>(Xq, A0, nullptr, adj, off, invd, n);

  fused_gemm_kernel<<<nstrip, 512, 0, stream>>>(A0, Bt1, Bt2, bias1, bias2, out, Zq, n);

  agg_fp8_kernel<1><<<(n + 3) / 4, 256, 0, stream>>>(Zq, nullptr, out, adj, off, invd, n);
}